// Round 8
// baseline (539.292 us; speedup 1.0000x reference)
//
#include <hip/hip_runtime.h>
#include <hip/hip_bf16.h>

// Problem constants
constexpr int Bn   = 512;   // batch
constexpr int SK   = 128;   // K seq len (== BLOCK)
constexpr int SV   = 261;   // V seq len
constexpr int Dd   = 768;   // feature dim
constexpr int Hh   = 58;    // head dim for Q/K projections
constexpr int OUTn = 512;   // output dim of Vt
constexpr int IMG  = 197;
constexpr int Mrows = Bn * SV;               // 133632
constexpr long long CTX_ELEMS = (long long)Mrows * OUTn; // 68,419,584

// ws layout (bytes)
constexpr size_t WS_HOT = 0;        // 512 f32
constexpr size_t WS_WB  = 4096;     // 512*768 bf16

typedef __attribute__((ext_vector_type(8))) short short8;
typedef __attribute__((ext_vector_type(4))) float floatx4;

__device__ __forceinline__ short f2bf(float f) {
    return __builtin_bit_cast(short, __float2bfloat16(f));
}

__device__ __forceinline__ float sigmoidf_(float x) {
    return 1.0f / (1.0f + __expf(-x));
}

template <int N>
__device__ __forceinline__ void wait_vm() {
    asm volatile("s_waitcnt vmcnt(%0)" :: "n"(N) : "memory");
}

// ---------------- Kernel B: fused Qt/u/c + scores -> attn (out) + hot ----------------
__global__ void __launch_bounds__(512) scores_fused(
    const float* __restrict__ Q, const float* __restrict__ K,
    const float* __restrict__ Wq, const float* __restrict__ bq,
    const float* __restrict__ Wk, const float* __restrict__ bk,
    const float* __restrict__ Wsw, const float* __restrict__ bsw,
    float* __restrict__ attn_out, float* __restrict__ hot)
{
    int b = blockIdx.x;
    int t = threadIdx.x, lane = t & 63, w = t >> 6; // 8 waves

    __shared__ __align__(16) float qrow[Dd];
    __shared__ float qt[64];
    __shared__ __align__(16) float ul[Dd];
    __shared__ float al[SK];
    __shared__ float cbs;

    qrow[t] = Q[b * Dd + t];
    if (t < Dd - 512) qrow[t + 512] = Q[b * Dd + t + 512];
    __syncthreads();

    // qt[h] = Q[b]·Wq[h] + bq[h]
    for (int h = w; h < Hh; h += 8) {
        const float4* wr4 = (const float4*)(Wq + (size_t)h * Dd);
        const float4* q4  = (const float4*)qrow;
        float s = 0.f;
        #pragma unroll
        for (int j = 0; j < 3; ++j) {
            float4 a = q4[lane + 64 * j], c = wr4[lane + 64 * j];
            s += a.x * c.x + a.y * c.y + a.z * c.z + a.w * c.w;
        }
        #pragma unroll
        for (int off = 32; off; off >>= 1) s += __shfl_down(s, off);
        if (lane == 0) qt[h] = s + bq[h];
    }
    __syncthreads();

    // u[d] = sum_h qt[h]*Wk[h,d] ; c = qt·bk
    for (int d = t; d < Dd; d += 512) {
        float s = 0.f;
        #pragma unroll 2
        for (int h = 0; h < Hh; ++h) s += qt[h] * Wk[(size_t)h * Dd + d];
        ul[d] = s;
    }
    if (w == 0) {
        float v = (lane < Hh) ? qt[lane] * bk[lane] : 0.f;
        #pragma unroll
        for (int off = 32; off; off >>= 1) v += __shfl_down(v, off);
        if (lane == 0) cbs = v;
    }
    __syncthreads();

    float cb = cbs;
    const float4* Kb4 = (const float4*)(K + (size_t)b * SK * Dd);
    const float4* u4  = (const float4*)ul;
    for (int k = w; k < SK; k += 8) {
        const float4* kr4 = Kb4 + (size_t)k * (Dd / 4);
        float s = 0.f;
        #pragma unroll
        for (int j = 0; j < 3; ++j) {
            float4 a = kr4[lane + 64 * j], c = u4[lane + 64 * j];
            s += a.x * c.x + a.y * c.y + a.z * c.z + a.w * c.w;
        }
        #pragma unroll
        for (int off = 32; off; off >>= 1) s += __shfl_down(s, off);
        if (lane == 0) {
            float sc = (s + cb) * 0.0883883476483184f; // 1/sqrt(128)
            float a = sigmoidf_(sc);
            attn_out[(size_t)b * SK + k] = a;
            al[k] = a;
        }
    }
    __syncthreads();

    if (w == 0) {
        float v = al[lane] * Wsw[lane] + al[lane + 64] * Wsw[lane + 64];
        #pragma unroll
        for (int off = 32; off; off >>= 1) v += __shfl_down(v, off);
        if (lane == 0) hot[b] = sigmoidf_(v + bsw[0]);
    }
}

// ---------------- Kernel D: Wv f32 -> bf16, MFMA-fragment-major layout ----------------
// Chunk index = kb*32 + g (g = col>>4); within chunk lane = ((k>>3)&3)*16 + (col&15),
// 8 consecutive bf16 k's per lane -> fragment = one coalesced dwordx4 per wave.
__global__ void __launch_bounds__(256) wv_convert(
    const float* __restrict__ Wv, unsigned short* __restrict__ wsB)
{
    int t = blockIdx.x * 256 + threadIdx.x;
    if (t >= OUTn * Dd) return;
    int col = t / Dd;
    int k   = t - col * Dd;
    int kb = k >> 5, kgrp = (k >> 3) & 3, kj = k & 7;
    int g = col >> 4, cl = col & 15;
    size_t off = ((size_t)(kb * 32 + g) * 64 + (kgrp * 16 + cl)) * 8 + kj;
    wsB[off] = (unsigned short)f2bf(Wv[t]);
}

// ---------------- Kernel C: context = scale(b,s) * (V·Wv^T + bv) ----------------
// BM=64, BN=256, 4 waves (1m x 4n, wave tile 64x64). NO LDS, NO barriers:
// reg-staged A (f32) + B (bf16 fragments), fence-enforced double-buffering with
// counted vmcnt(12); consume-then-issue so the same buffer parity is reused.
// __launch_bounds__(256,2): 256-VGPR cap (kernel needs ~200) -> NO SPILL.
// (R6's (256,6) forced an ~85-reg cap -> total scratch spill, 2.9ms. The plain
// global-load path is the point: it has much deeper per-CU outstanding-miss
// capacity than the global_load_lds DMA queue, which pinned R3-R7 at ~13 GB/s/CU.)
__global__ void __launch_bounds__(256, 2) ctx_gemm(
    const float* __restrict__ V, const unsigned short* __restrict__ wsB,
    const float* __restrict__ bv, const float* __restrict__ hot,
    float* __restrict__ out)
{
    // XCD swizzle: 4176 blocks = 8 * 522; nt-pairs (same A rows) on one XCD.
    int bid = (blockIdx.x >> 3) + (blockIdx.x & 7) * 522;
    int nt = bid & 1;
    int mt = bid >> 1;
    int t = threadIdx.x, lane = t & 63, wn = t >> 6;
    int m_base = mt * 64;

    // A fragment rows: row = mr*16 + (lane&15), k-group = (lane>>4)*8 (8 consecutive f32)
    const float* arow[4];
    #pragma unroll
    for (int mr = 0; mr < 4; ++mr)
        arow[mr] = V + (size_t)(m_base + mr * 16 + (lane & 15)) * Dd + ((lane >> 4) * 8);

    const unsigned short* bB = wsB + ((size_t)(nt * 16 + wn * 4) * 64 + lane) * 8;

    floatx4 acc[4][4] = {};
    float4 pa[2][8];
    short8 pb[2][4];

// Issue one K-step's loads into buffer BUF (4 B dwordx4 + 8 A dwordx4).
#define LOADS(T, BUF)                                                              \
  {                                                                                \
    _Pragma("unroll")                                                              \
    for (int nr = 0; nr < 4; ++nr)                                                 \
      pb[BUF][nr] = *(const short8*)(bB + ((size_t)(T) * 32 + nr) * 512);          \
    _Pragma("unroll")                                                              \
    for (int mr = 0; mr < 4; ++mr) {                                               \
      pa[BUF][2 * mr]     = *(const float4*)(arow[mr] + (T) * 32);                 \
      pa[BUF][2 * mr + 1] = *(const float4*)(arow[mr] + (T) * 32 + 4);             \
    }                                                                              \
  }

    // Prologue: two steps in flight (24 outstanding vmem ops).
    LOADS(0, 0)
    __builtin_amdgcn_sched_barrier(0);
    LOADS(1, 1)
    __builtin_amdgcn_sched_barrier(0);

// Step T: wait vm(12) (retires step T's 12 ops, keeps T+1's 12 in flight) ->
// cvt+MFMA on buffer T&1 -> re-issue T+2 into the freed buffer T&1.
#define KSTEP(T, VM, DOLOAD)                                                       \
  {                                                                                \
    wait_vm<VM>();                                                                 \
    __builtin_amdgcn_sched_barrier(0);                                             \
    short8 af[4];                                                                  \
    _Pragma("unroll")                                                              \
    for (int mr = 0; mr < 4; ++mr) {                                               \
      float4 f0 = pa[(T) & 1][2 * mr], f1 = pa[(T) & 1][2 * mr + 1];               \
      af[mr][0] = f2bf(f0.x); af[mr][1] = f2bf(f0.y);                              \
      af[mr][2] = f2bf(f0.z); af[mr][3] = f2bf(f0.w);                              \
      af[mr][4] = f2bf(f1.x); af[mr][5] = f2bf(f1.y);                              \
      af[mr][6] = f2bf(f1.z); af[mr][7] = f2bf(f1.w);                              \
    }                                                                              \
    __builtin_amdgcn_s_setprio(1);                                                 \
    _Pragma("unroll")                                                              \
    for (int mr = 0; mr < 4; ++mr) {                                               \
      _Pragma("unroll")                                                            \
      for (int nr = 0; nr < 4; ++nr)                                               \
        acc[mr][nr] = __builtin_amdgcn_mfma_f32_16x16x32_bf16(af[mr],              \
                          pb[(T) & 1][nr], acc[mr][nr], 0, 0, 0);                  \
    }                                                                              \
    __builtin_amdgcn_s_setprio(0);                                                 \
    __builtin_amdgcn_sched_barrier(0);                                             \
    if (DOLOAD) { LOADS((T) + 2, (T) & 1) }                                        \
    __builtin_amdgcn_sched_barrier(0);                                             \
  }

    KSTEP(0,  12, 1)
    KSTEP(1,  12, 1)
    KSTEP(2,  12, 1)
    KSTEP(3,  12, 1)
    KSTEP(4,  12, 1)
    KSTEP(5,  12, 1)
    KSTEP(6,  12, 1)
    KSTEP(7,  12, 1)
    KSTEP(8,  12, 1)
    KSTEP(9,  12, 1)
    KSTEP(10, 12, 1)
    KSTEP(11, 12, 1)
    KSTEP(12, 12, 1)
    KSTEP(13, 12, 1)
    KSTEP(14, 12, 1)
    KSTEP(15, 12, 1)
    KSTEP(16, 12, 1)
    KSTEP(17, 12, 1)
    KSTEP(18, 12, 1)
    KSTEP(19, 12, 1)
    KSTEP(20, 12, 1)
    KSTEP(21, 12, 1)
    KSTEP(22, 12, 0)
    KSTEP(23, 0,  0)
#undef KSTEP
#undef LOADS

    // Epilogue: out[m,n] = scale(b,s) * (acc + bv[n]); C/D: col=lane&15, row=(lane>>4)*4+reg
    float bvv[4];
    #pragma unroll
    for (int nr = 0; nr < 4; ++nr)
        bvv[nr] = bv[nt * 256 + wn * 64 + nr * 16 + (lane & 15)];

    int ncol0 = nt * 256 + wn * 64 + (lane & 15);
    #pragma unroll
    for (int mr = 0; mr < 4; ++mr) {
        #pragma unroll
        for (int rg = 0; rg < 4; ++rg) {
            int m = m_base + mr * 16 + ((lane >> 4) << 2) + rg;
            int b = m / 261;
            int s = m - b * 261;
            float h = hot[b];
            float scale = (s < IMG) ? h : (1.0f - h);
            float* orow = out + (size_t)m * OUTn + ncol0;
            #pragma unroll
            for (int nr = 0; nr < 4; ++nr)
                orow[nr * 16] = scale * (acc[mr][nr][rg] + bvv[nr]);
        }
    }
}

extern "C" void kernel_launch(void* const* d_in, const int* in_sizes, int n_in,
                              void* d_out, int out_size, void* d_ws, size_t ws_size,
                              hipStream_t stream) {
    const float* Q   = (const float*)d_in[0];
    const float* K   = (const float*)d_in[1];
    const float* V   = (const float*)d_in[2];
    const float* Wq  = (const float*)d_in[3];
    const float* bq  = (const float*)d_in[4];
    const float* Wk  = (const float*)d_in[5];
    const float* bk  = (const float*)d_in[6];
    const float* Wsw = (const float*)d_in[7];
    const float* bsw = (const float*)d_in[8];
    const float* Wv  = (const float*)d_in[9];
    const float* bv  = (const float*)d_in[10];

    float* out = (float*)d_out;
    char* ws = (char*)d_ws;
    float* hot = (float*)(ws + WS_HOT);
    unsigned short* wsB = (unsigned short*)(ws + WS_WB);

    hipLaunchKernelGGL(wv_convert, dim3((OUTn * Dd + 255) / 256), dim3(256), 0, stream, Wv, wsB);
    hipLaunchKernelGGL(scores_fused, dim3(Bn), dim3(512), 0, stream,
                       Q, K, Wq, bq, Wk, bk, Wsw, bsw, out + CTX_ELEMS, hot);
    hipLaunchKernelGGL(ctx_gemm, dim3((Mrows / 64) * 2), dim3(256), 0, stream, V, wsB, bv, hot, out);
}

// Round 9
// 533.707 us; speedup vs baseline: 1.0105x; 1.0105x over previous
//
#include <hip/hip_runtime.h>
#include <hip/hip_bf16.h>

// Problem constants
constexpr int Bn   = 512;   // batch
constexpr int SK   = 128;   // K seq len (== BLOCK)
constexpr int SV   = 261;   // V seq len
constexpr int Dd   = 768;   // feature dim
constexpr int Hh   = 58;    // head dim for Q/K projections
constexpr int OUTn = 512;   // output dim of Vt
constexpr int IMG  = 197;
constexpr int Mrows = Bn * SV;               // 133632
constexpr long long CTX_ELEMS = (long long)Mrows * OUTn; // 68,419,584

// ws layout (bytes)
constexpr size_t WS_HOT = 0;        // 512 f32
constexpr size_t WS_WB  = 4096;     // 512*768 bf16

typedef __attribute__((ext_vector_type(8))) short short8;
typedef __attribute__((ext_vector_type(4))) float floatx4;
typedef __attribute__((ext_vector_type(4))) unsigned int uintx4;

__device__ __forceinline__ short f2bf(float f) {
    return __builtin_bit_cast(short, __float2bfloat16(f));
}

__device__ __forceinline__ float sigmoidf_(float x) {
    return 1.0f / (1.0f + __expf(-x));
}

template <int N>
__device__ __forceinline__ void wait_vm() {
    asm volatile("s_waitcnt vmcnt(%0)" :: "n"(N) : "memory");
}

// Inline-asm global loads: the compiler CANNOT sink/remat these (R2/R8 failure
// mode), and they are invisible to its vmcnt tracking -> our counted waits are
// the only waits. Output regs are live from issue to consumption = true staging.
__device__ __forceinline__ float4 gload4f(const float* p) {
    float4 r;
    asm volatile("global_load_dwordx4 %0, %1, off" : "=v"(r) : "v"(p));
    return r;
}
__device__ __forceinline__ short8 gload8h(const unsigned short* p) {
    short8 r;
    asm volatile("global_load_dwordx4 %0, %1, off" : "=v"(r) : "v"(p));
    return r;
}
__device__ __forceinline__ unsigned cvt_pk_bf16(float lo, float hi) {
    unsigned r;
    asm("v_cvt_pk_bf16_f32 %0, %1, %2" : "=v"(r) : "v"(lo), "v"(hi));
    return r;
}

// ---------------- Kernel B: fused Qt/u/c + scores -> attn (out) + hot ----------------
__global__ void __launch_bounds__(512) scores_fused(
    const float* __restrict__ Q, const float* __restrict__ K,
    const float* __restrict__ Wq, const float* __restrict__ bq,
    const float* __restrict__ Wk, const float* __restrict__ bk,
    const float* __restrict__ Wsw, const float* __restrict__ bsw,
    float* __restrict__ attn_out, float* __restrict__ hot)
{
    int b = blockIdx.x;
    int t = threadIdx.x, lane = t & 63, w = t >> 6; // 8 waves

    __shared__ __align__(16) float qrow[Dd];
    __shared__ float qt[64];
    __shared__ __align__(16) float ul[Dd];
    __shared__ float al[SK];
    __shared__ float cbs;

    qrow[t] = Q[b * Dd + t];
    if (t < Dd - 512) qrow[t + 512] = Q[b * Dd + t + 512];
    __syncthreads();

    // qt[h] = Q[b]·Wq[h] + bq[h]
    for (int h = w; h < Hh; h += 8) {
        const float4* wr4 = (const float4*)(Wq + (size_t)h * Dd);
        const float4* q4  = (const float4*)qrow;
        float s = 0.f;
        #pragma unroll
        for (int j = 0; j < 3; ++j) {
            float4 a = q4[lane + 64 * j], c = wr4[lane + 64 * j];
            s += a.x * c.x + a.y * c.y + a.z * c.z + a.w * c.w;
        }
        #pragma unroll
        for (int off = 32; off; off >>= 1) s += __shfl_down(s, off);
        if (lane == 0) qt[h] = s + bq[h];
    }
    __syncthreads();

    // u[d] = sum_h qt[h]*Wk[h,d] ; c = qt·bk
    for (int d = t; d < Dd; d += 512) {
        float s = 0.f;
        #pragma unroll 2
        for (int h = 0; h < Hh; ++h) s += qt[h] * Wk[(size_t)h * Dd + d];
        ul[d] = s;
    }
    if (w == 0) {
        float v = (lane < Hh) ? qt[lane] * bk[lane] : 0.f;
        #pragma unroll
        for (int off = 32; off; off >>= 1) v += __shfl_down(v, off);
        if (lane == 0) cbs = v;
    }
    __syncthreads();

    float cb = cbs;
    const float4* Kb4 = (const float4*)(K + (size_t)b * SK * Dd);
    const float4* u4  = (const float4*)ul;
    for (int k = w; k < SK; k += 8) {
        const float4* kr4 = Kb4 + (size_t)k * (Dd / 4);
        float s = 0.f;
        #pragma unroll
        for (int j = 0; j < 3; ++j) {
            float4 a = kr4[lane + 64 * j], c = u4[lane + 64 * j];
            s += a.x * c.x + a.y * c.y + a.z * c.z + a.w * c.w;
        }
        #pragma unroll
        for (int off = 32; off; off >>= 1) s += __shfl_down(s, off);
        if (lane == 0) {
            float sc = (s + cb) * 0.0883883476483184f; // 1/sqrt(128)
            float a = sigmoidf_(sc);
            attn_out[(size_t)b * SK + k] = a;
            al[k] = a;
        }
    }
    __syncthreads();

    if (w == 0) {
        float v = al[lane] * Wsw[lane] + al[lane + 64] * Wsw[lane + 64];
        #pragma unroll
        for (int off = 32; off; off >>= 1) v += __shfl_down(v, off);
        if (lane == 0) hot[b] = sigmoidf_(v + bsw[0]);
    }
}

// ---------------- Kernel D: Wv f32 -> bf16, MFMA-fragment-major layout ----------------
__global__ void __launch_bounds__(256) wv_convert(
    const float* __restrict__ Wv, unsigned short* __restrict__ wsB)
{
    int t = blockIdx.x * 256 + threadIdx.x;
    if (t >= OUTn * Dd) return;
    int col = t / Dd;
    int k   = t - col * Dd;
    int kb = k >> 5, kgrp = (k >> 3) & 3, kj = k & 7;
    int g = col >> 4, cl = col & 15;
    size_t off = ((size_t)(kb * 32 + g) * 64 + (kgrp * 16 + cl)) * 8 + kj;
    wsB[off] = (unsigned short)f2bf(Wv[t]);
}

// ---------------- Kernel C: context = scale(b,s) * (V·Wv^T + bv) ----------------
// BM=64, BN=256, 4 waves (1m x 4n, wave tile 64x64). No LDS, no barriers.
// TRUE register double-buffer via inline-asm global_load_dwordx4 (un-sinkable,
// un-rematerializable); counted vmcnt(12) retires exactly the previous step's
// 12 loads. 8 waves/CU x 12KB in flight = 96KB/CU >> 22KB BDP.
__global__ void __launch_bounds__(256, 2) ctx_gemm(
    const float* __restrict__ V, const unsigned short* __restrict__ wsB,
    const float* __restrict__ bv, const float* __restrict__ hot,
    float* __restrict__ out)
{
    // XCD swizzle: 4176 blocks = 8 * 522; nt-pairs (same A rows) on one XCD.
    int bid = (blockIdx.x >> 3) + (blockIdx.x & 7) * 522;
    int nt = bid & 1;
    int mt = bid >> 1;
    int t = threadIdx.x, lane = t & 63, wn = t >> 6;
    int m_base = mt * 64;

    // A fragment rows: row = mr*16 + (lane&15), k-group = (lane>>4)*8
    const float* arow[4];
    #pragma unroll
    for (int mr = 0; mr < 4; ++mr)
        arow[mr] = V + (size_t)(m_base + mr * 16 + (lane & 15)) * Dd + ((lane >> 4) * 8);

    const unsigned short* bB = wsB + ((size_t)(nt * 16 + wn * 4) * 64 + lane) * 8;

    floatx4 acc[4][4] = {};
    float4 pa[2][8];
    short8 pb[2][4];

// Issue one K-step's 12 loads into buffer BUF (B x4 then A x8; order fixed by
// asm volatile emission order -> vmcnt ledger is exact).
#define LOADS(T, BUF)                                                              \
  {                                                                                \
    _Pragma("unroll")                                                              \
    for (int nr = 0; nr < 4; ++nr)                                                 \
      pb[BUF][nr] = gload8h(bB + ((size_t)(T) * 32 + nr) * 512);                   \
    _Pragma("unroll")                                                              \
    for (int mr = 0; mr < 4; ++mr) {                                               \
      pa[BUF][2 * mr]     = gload4f(arow[mr] + (T) * 32);                          \
      pa[BUF][2 * mr + 1] = gload4f(arow[mr] + (T) * 32 + 4);                      \
    }                                                                              \
  }

    // Prologue: two steps in flight (24 outstanding vmem ops).
    LOADS(0, 0)
    LOADS(1, 1)

// Step T: vm(12) retires step T's 12 ops (T+1's stay in flight) -> cvt_pk ->
// 16 MFMA -> issue T+2 into freed buffer.
#define KSTEP(T, VM, DOLOAD)                                                       \
  {                                                                                \
    wait_vm<VM>();                                                                 \
    __builtin_amdgcn_sched_barrier(0);                                             \
    short8 af[4];                                                                  \
    _Pragma("unroll")                                                              \
    for (int mr = 0; mr < 4; ++mr) {                                               \
      float4 f0 = pa[(T) & 1][2 * mr], f1 = pa[(T) & 1][2 * mr + 1];               \
      uintx4 u;                                                                    \
      u[0] = cvt_pk_bf16(f0.x, f0.y);                                              \
      u[1] = cvt_pk_bf16(f0.z, f0.w);                                              \
      u[2] = cvt_pk_bf16(f1.x, f1.y);                                              \
      u[3] = cvt_pk_bf16(f1.z, f1.w);                                              \
      af[mr] = __builtin_bit_cast(short8, u);                                      \
    }                                                                              \
    __builtin_amdgcn_s_setprio(1);                                                 \
    _Pragma("unroll")                                                              \
    for (int mr = 0; mr < 4; ++mr) {                                               \
      _Pragma("unroll")                                                            \
      for (int nr = 0; nr < 4; ++nr)                                               \
        acc[mr][nr] = __builtin_amdgcn_mfma_f32_16x16x32_bf16(af[mr],              \
                          pb[(T) & 1][nr], acc[mr][nr], 0, 0, 0);                  \
    }                                                                              \
    __builtin_amdgcn_s_setprio(0);                                                 \
    __builtin_amdgcn_sched_barrier(0);                                             \
    if (DOLOAD) { LOADS((T) + 2, (T) & 1) }                                        \
    __builtin_amdgcn_sched_barrier(0);                                             \
  }

    KSTEP(0,  12, 1)
    KSTEP(1,  12, 1)
    KSTEP(2,  12, 1)
    KSTEP(3,  12, 1)
    KSTEP(4,  12, 1)
    KSTEP(5,  12, 1)
    KSTEP(6,  12, 1)
    KSTEP(7,  12, 1)
    KSTEP(8,  12, 1)
    KSTEP(9,  12, 1)
    KSTEP(10, 12, 1)
    KSTEP(11, 12, 1)
    KSTEP(12, 12, 1)
    KSTEP(13, 12, 1)
    KSTEP(14, 12, 1)
    KSTEP(15, 12, 1)
    KSTEP(16, 12, 1)
    KSTEP(17, 12, 1)
    KSTEP(18, 12, 1)
    KSTEP(19, 12, 1)
    KSTEP(20, 12, 1)
    KSTEP(21, 12, 1)
    KSTEP(22, 12, 0)
    KSTEP(23, 0,  0)
#undef KSTEP
#undef LOADS

    // Epilogue: out[m,n] = scale(b,s) * (acc + bv[n]); C/D: col=lane&15, row=(lane>>4)*4+reg
    float bvv[4];
    #pragma unroll
    for (int nr = 0; nr < 4; ++nr)
        bvv[nr] = bv[nt * 256 + wn * 64 + nr * 16 + (lane & 15)];

    int ncol0 = nt * 256 + wn * 64 + (lane & 15);
    #pragma unroll
    for (int mr = 0; mr < 4; ++mr) {
        #pragma unroll
        for (int rg = 0; rg < 4; ++rg) {
            int m = m_base + mr * 16 + ((lane >> 4) << 2) + rg;
            int b = m / 261;
            int s = m - b * 261;
            float h = hot[b];
            float scale = (s < IMG) ? h : (1.0f - h);
            float* orow = out + (size_t)m * OUTn + ncol0;
            #pragma unroll
            for (int nr = 0; nr < 4; ++nr)
                orow[nr * 16] = scale * (acc[mr][nr][rg] + bvv[nr]);
        }
    }
}

extern "C" void kernel_launch(void* const* d_in, const int* in_sizes, int n_in,
                              void* d_out, int out_size, void* d_ws, size_t ws_size,
                              hipStream_t stream) {
    const float* Q   = (const float*)d_in[0];
    const float* K   = (const float*)d_in[1];
    const float* V   = (const float*)d_in[2];
    const float* Wq  = (const float*)d_in[3];
    const float* bq  = (const float*)d_in[4];
    const float* Wk  = (const float*)d_in[5];
    const float* bk  = (const float*)d_in[6];
    const float* Wsw = (const float*)d_in[7];
    const float* bsw = (const float*)d_in[8];
    const float* Wv  = (const float*)d_in[9];
    const float* bv  = (const float*)d_in[10];

    float* out = (float*)d_out;
    char* ws = (char*)d_ws;
    float* hot = (float*)(ws + WS_HOT);
    unsigned short* wsB = (unsigned short*)(ws + WS_WB);

    hipLaunchKernelGGL(wv_convert, dim3((OUTn * Dd + 255) / 256), dim3(256), 0, stream, Wv, wsB);
    hipLaunchKernelGGL(scores_fused, dim3(Bn), dim3(512), 0, stream,
                       Q, K, Wq, bq, Wk, bk, Wsw, bsw, out + CTX_ELEMS, hot);
    hipLaunchKernelGGL(ctx_gemm, dim3((Mrows / 64) * 2), dim3(256), 0, stream, V, wsB, bv, hot, out);
}

// Round 10
// 314.398 us; speedup vs baseline: 1.7153x; 1.6976x over previous
//
#include <hip/hip_runtime.h>
#include <hip/hip_bf16.h>

// Problem constants
constexpr int Bn   = 512;   // batch
constexpr int SK   = 128;   // K seq len (== BLOCK)
constexpr int SV   = 261;   // V seq len
constexpr int Dd   = 768;   // feature dim
constexpr int Hh   = 58;    // head dim for Q/K projections
constexpr int OUTn = 512;   // output dim of Vt
constexpr int IMG  = 197;
constexpr int Mrows = Bn * SV;               // 133632
constexpr long long CTX_ELEMS = (long long)Mrows * OUTn; // 68,419,584

// ws layout (bytes)
constexpr size_t WS_HOT = 0;        // 512 f32
constexpr size_t WS_WB  = 4096;     // 512*768 bf16

typedef __attribute__((ext_vector_type(8))) short short8;
typedef __attribute__((ext_vector_type(4))) float floatx4;

__device__ __forceinline__ short f2bf(float f) {
    return __builtin_bit_cast(short, __float2bfloat16(f));
}

__device__ __forceinline__ float sigmoidf_(float x) {
    return 1.0f / (1.0f + __expf(-x));
}

template <int N>
__device__ __forceinline__ void wait_vm() {
    asm volatile("s_waitcnt vmcnt(%0)" :: "n"(N) : "memory");
}

__device__ __forceinline__ float4 gload4f(const float* p) {
    float4 r;
    asm volatile("global_load_dwordx4 %0, %1, off" : "=v"(r) : "v"(p));
    return r;
}
__device__ __forceinline__ short8 gload8h(const unsigned short* p) {
    short8 r;
    asm volatile("global_load_dwordx4 %0, %1, off" : "=v"(r) : "v"(p));
    return r;
}
__device__ __forceinline__ unsigned cvt_pk_bf16(float lo, float hi) {
    unsigned r;
    asm("v_cvt_pk_bf16_f32 %0, %1, %2" : "=v"(r) : "v"(lo), "v"(hi));
    return r;
}

// ---------------- Kernel B: fused Qt/u/c + scores -> attn (out) + hot ----------------
__global__ void __launch_bounds__(512) scores_fused(
    const float* __restrict__ Q, const float* __restrict__ K,
    const float* __restrict__ Wq, const float* __restrict__ bq,
    const float* __restrict__ Wk, const float* __restrict__ bk,
    const float* __restrict__ Wsw, const float* __restrict__ bsw,
    float* __restrict__ attn_out, float* __restrict__ hot)
{
    int b = blockIdx.x;
    int t = threadIdx.x, lane = t & 63, w = t >> 6; // 8 waves

    __shared__ __align__(16) float qrow[Dd];
    __shared__ float qt[64];
    __shared__ __align__(16) float ul[Dd];
    __shared__ float al[SK];
    __shared__ float cbs;

    qrow[t] = Q[b * Dd + t];
    if (t < Dd - 512) qrow[t + 512] = Q[b * Dd + t + 512];
    __syncthreads();

    for (int h = w; h < Hh; h += 8) {
        const float4* wr4 = (const float4*)(Wq + (size_t)h * Dd);
        const float4* q4  = (const float4*)qrow;
        float s = 0.f;
        #pragma unroll
        for (int j = 0; j < 3; ++j) {
            float4 a = q4[lane + 64 * j], c = wr4[lane + 64 * j];
            s += a.x * c.x + a.y * c.y + a.z * c.z + a.w * c.w;
        }
        #pragma unroll
        for (int off = 32; off; off >>= 1) s += __shfl_down(s, off);
        if (lane == 0) qt[h] = s + bq[h];
    }
    __syncthreads();

    for (int d = t; d < Dd; d += 512) {
        float s = 0.f;
        #pragma unroll 2
        for (int h = 0; h < Hh; ++h) s += qt[h] * Wk[(size_t)h * Dd + d];
        ul[d] = s;
    }
    if (w == 0) {
        float v = (lane < Hh) ? qt[lane] * bk[lane] : 0.f;
        #pragma unroll
        for (int off = 32; off; off >>= 1) v += __shfl_down(v, off);
        if (lane == 0) cbs = v;
    }
    __syncthreads();

    float cb = cbs;
    const float4* Kb4 = (const float4*)(K + (size_t)b * SK * Dd);
    const float4* u4  = (const float4*)ul;
    for (int k = w; k < SK; k += 8) {
        const float4* kr4 = Kb4 + (size_t)k * (Dd / 4);
        float s = 0.f;
        #pragma unroll
        for (int j = 0; j < 3; ++j) {
            float4 a = kr4[lane + 64 * j], c = u4[lane + 64 * j];
            s += a.x * c.x + a.y * c.y + a.z * c.z + a.w * c.w;
        }
        #pragma unroll
        for (int off = 32; off; off >>= 1) s += __shfl_down(s, off);
        if (lane == 0) {
            float sc = (s + cb) * 0.0883883476483184f; // 1/sqrt(128)
            float a = sigmoidf_(sc);
            attn_out[(size_t)b * SK + k] = a;
            al[k] = a;
        }
    }
    __syncthreads();

    if (w == 0) {
        float v = al[lane] * Wsw[lane] + al[lane + 64] * Wsw[lane + 64];
        #pragma unroll
        for (int off = 32; off; off >>= 1) v += __shfl_down(v, off);
        if (lane == 0) hot[b] = sigmoidf_(v + bsw[0]);
    }
}

// ---------------- Kernel D: Wv f32 -> bf16, MFMA-fragment-major layout ----------------
__global__ void __launch_bounds__(256) wv_convert(
    const float* __restrict__ Wv, unsigned short* __restrict__ wsB)
{
    int t = blockIdx.x * 256 + threadIdx.x;
    if (t >= OUTn * Dd) return;
    int col = t / Dd;
    int k   = t - col * Dd;
    int kb = k >> 5, kgrp = (k >> 3) & 3, kj = k & 7;
    int g = col >> 4, cl = col & 15;
    size_t off = ((size_t)(kb * 32 + g) * 64 + (kgrp * 16 + cl)) * 8 + kj;
    wsB[off] = (unsigned short)f2bf(Wv[t]);
}

// ---------------- Kernel C: producer/consumer GEMM ----------------
// BM=128, BN=128 (4 n-tiles, XCD-grouped -> L2 absorbs A re-reads).
// 384 thr = 6 waves: waves 0-3 consumers (64x64 tiles), waves 4-5 producers.
// Producers: stream A (V f32) via asm loads (depth-2, vm(8)), cvt to bf16,
// ds_write into fragment-major LDS (8 frags x 1KB per buffer, double-buffered).
// Consumers: ds_read A-frags + asm-load B from L2-resident ws (vm(4) ledger)
// + 16 MFMA; never wait on an HBM miss. One s_barrier per K-step.
__global__ void __launch_bounds__(384, 3) ctx_gemm(
    const float* __restrict__ V, const unsigned short* __restrict__ wsB,
    const float* __restrict__ bv, const float* __restrict__ hot,
    float* __restrict__ out)
{
    // XCD swizzle: 4176 = 8*522; the 4 nt-siblings of an mt stay on one XCD.
    int bid = (blockIdx.x >> 3) + (blockIdx.x & 7) * 522;
    int nt = bid & 3;
    int mt = bid >> 2;                 // 0..1043
    int t = threadIdx.x, lane = t & 63, w = t >> 6;
    int m_base = mt * 128;

    __shared__ unsigned short ldsA[2][4096];   // 2 x 8KB: 8 frags x 512 u16

    if (w >= 4) {
        // ================= PRODUCER (waves 4,5) =================
        int p = w & 1;                 // half: rows p*64 .. p*64+63
        int r8 = lane >> 3;            // row within 8-row group
        int q  = lane & 7;             // 16B f32 granule (k 4-block)
        const float* srcA = V + (size_t)(m_base + p * 64 + r8) * Dd + q * 4;

        // LDS write offset for load i (8-row group), this lane:
        // frag = p*4 + (i>>1); elem = ((q>>1)*16 + (i&1)*8 + r8); byte = elem*16 + (q&1)*8
        unsigned wofs[8];
        #pragma unroll
        for (int i = 0; i < 8; ++i)
            wofs[i] = (unsigned)((p * 4 + (i >> 1)) * 1024
                     + ((q >> 1) * 16 + (i & 1) * 8 + r8) * 16 + (q & 1) * 8);

        float4 st[2][8];

#define PISSUE(T, BUF)                                                             \
    { _Pragma("unroll")                                                            \
      for (int i = 0; i < 8; ++i)                                                  \
        st[BUF][i] = gload4f(srcA + (size_t)(T) * 32 + (size_t)i * 8 * Dd); }

#define PWRITE(T, BUF)                                                             \
    { char* base = (char*)&ldsA[(T) & 1][0];                                       \
      _Pragma("unroll")                                                            \
      for (int i = 0; i < 8; ++i) {                                                \
        uint2 d2;                                                                  \
        d2.x = cvt_pk_bf16(st[BUF][i].x, st[BUF][i].y);                            \
        d2.y = cvt_pk_bf16(st[BUF][i].z, st[BUF][i].w);                            \
        *(uint2*)(base + wofs[i]) = d2;                                            \
      }                                                                            \
      asm volatile("s_waitcnt lgkmcnt(0)" ::: "memory"); }

        // Prologue: issue L0,L1; retire L0; write W0.
        PISSUE(0, 0)
        PISSUE(1, 1)
        wait_vm<8>();
        __builtin_amdgcn_sched_barrier(0);
        PWRITE(0, 0)
        __builtin_amdgcn_s_barrier();

#define PSTEP(T)                                                                   \
    {                                                                              \
      if ((T) <= 21) PISSUE((T) + 2, (T) & 1)                                      \
      if ((T) <= 22) {                                                             \
        wait_vm<((T) <= 21 ? 8 : 0)>();                                            \
        __builtin_amdgcn_sched_barrier(0);                                         \
        PWRITE((T) + 1, ((T) + 1) & 1)                                             \
      }                                                                            \
      __builtin_amdgcn_s_barrier();                                                \
    }

        PSTEP(0)  PSTEP(1)  PSTEP(2)  PSTEP(3)  PSTEP(4)  PSTEP(5)
        PSTEP(6)  PSTEP(7)  PSTEP(8)  PSTEP(9)  PSTEP(10) PSTEP(11)
        PSTEP(12) PSTEP(13) PSTEP(14) PSTEP(15) PSTEP(16) PSTEP(17)
        PSTEP(18) PSTEP(19) PSTEP(20) PSTEP(21) PSTEP(22) PSTEP(23)
#undef PSTEP
#undef PWRITE
#undef PISSUE
        return;
    }

    // ================= CONSUMER (waves 0..3) =================
    int cm = w >> 1, cn = w & 1;       // 2m x 2n, wave tile 64x64
    // B global fragments: frag = kb*32 + nt*8 + cn*4 + nr
    const unsigned short* bB = wsB + ((size_t)(nt * 8 + cn * 4) * 64 + lane) * 8;

    floatx4 acc[4][4] = {};
    short8 pbB[2][4];

#define CISSUE(T, BUF)                                                             \
    { _Pragma("unroll")                                                            \
      for (int nr = 0; nr < 4; ++nr)                                               \
        pbB[BUF][nr] = gload8h(bB + ((size_t)(T) * 32 + nr) * 512); }

    // Prologue: issue B0; wait for producers' W0.
    CISSUE(0, 0)
    __builtin_amdgcn_s_barrier();

#define CSTEP(T)                                                                   \
    {                                                                              \
      if ((T) <= 22) CISSUE((T) + 1, ((T) + 1) & 1)                                \
      const short8* a8 = (const short8*)&ldsA[(T) & 1][0];                         \
      short8 af[4];                                                                \
      _Pragma("unroll")                                                            \
      for (int mr = 0; mr < 4; ++mr)                                               \
        af[mr] = a8[(cm * 4 + mr) * 64 + lane];                                    \
      wait_vm<((T) <= 22 ? 4 : 0)>();                                              \
      __builtin_amdgcn_sched_barrier(0);                                           \
      __builtin_amdgcn_s_setprio(1);                                               \
      _Pragma("unroll")                                                            \
      for (int mr = 0; mr < 4; ++mr) {                                             \
        _Pragma("unroll")                                                          \
        for (int nr = 0; nr < 4; ++nr)                                             \
          acc[mr][nr] = __builtin_amdgcn_mfma_f32_16x16x32_bf16(af[mr],            \
                            pbB[(T) & 1][nr], acc[mr][nr], 0, 0, 0);               \
      }                                                                            \
      __builtin_amdgcn_s_setprio(0);                                               \
      __builtin_amdgcn_s_barrier();                                                \
    }

    CSTEP(0)  CSTEP(1)  CSTEP(2)  CSTEP(3)  CSTEP(4)  CSTEP(5)
    CSTEP(6)  CSTEP(7)  CSTEP(8)  CSTEP(9)  CSTEP(10) CSTEP(11)
    CSTEP(12) CSTEP(13) CSTEP(14) CSTEP(15) CSTEP(16) CSTEP(17)
    CSTEP(18) CSTEP(19) CSTEP(20) CSTEP(21) CSTEP(22) CSTEP(23)
#undef CSTEP
#undef CISSUE

    // Epilogue: out[m,n] = scale(b,s) * (acc + bv[n]); C/D: col=lane&15, row=(lane>>4)*4+reg
    float bvv[4];
    #pragma unroll
    for (int nr = 0; nr < 4; ++nr)
        bvv[nr] = bv[nt * 128 + cn * 64 + nr * 16 + (lane & 15)];

    int ncol0 = nt * 128 + cn * 64 + (lane & 15);
    #pragma unroll
    for (int mr = 0; mr < 4; ++mr) {
        #pragma unroll
        for (int rg = 0; rg < 4; ++rg) {
            int m = m_base + cm * 64 + mr * 16 + ((lane >> 4) << 2) + rg;
            int b = m / 261;
            int s = m - b * 261;
            float h = hot[b];
            float scale = (s < IMG) ? h : (1.0f - h);
            float* orow = out + (size_t)m * OUTn + ncol0;
            #pragma unroll
            for (int nr = 0; nr < 4; ++nr)
                orow[nr * 16] = scale * (acc[mr][nr][rg] + bvv[nr]);
        }
    }
}

extern "C" void kernel_launch(void* const* d_in, const int* in_sizes, int n_in,
                              void* d_out, int out_size, void* d_ws, size_t ws_size,
                              hipStream_t stream) {
    const float* Q   = (const float*)d_in[0];
    const float* K   = (const float*)d_in[1];
    const float* V   = (const float*)d_in[2];
    const float* Wq  = (const float*)d_in[3];
    const float* bq  = (const float*)d_in[4];
    const float* Wk  = (const float*)d_in[5];
    const float* bk  = (const float*)d_in[6];
    const float* Wsw = (const float*)d_in[7];
    const float* bsw = (const float*)d_in[8];
    const float* Wv  = (const float*)d_in[9];
    const float* bv  = (const float*)d_in[10];

    float* out = (float*)d_out;
    char* ws = (char*)d_ws;
    float* hot = (float*)(ws + WS_HOT);
    unsigned short* wsB = (unsigned short*)(ws + WS_WB);

    hipLaunchKernelGGL(wv_convert, dim3((OUTn * Dd + 255) / 256), dim3(256), 0, stream, Wv, wsB);
    hipLaunchKernelGGL(scores_fused, dim3(Bn), dim3(512), 0, stream,
                       Q, K, Wq, bq, Wk, bk, Wsw, bsw, out + CTX_ELEMS, hot);
    hipLaunchKernelGGL(ctx_gemm, dim3((Mrows / 128) * 4), dim3(384), 0, stream, V, wsB, bv, hot, out);
}